// Round 2
// baseline (10279.147 us; speedup 1.0000x reference)
//
#include <hip/hip_runtime.h>
#include <cstdint>
#include <cstddef>

// ---------------- problem constants ----------------
#define B_    64
#define L_    256
#define E_    768
#define H_    12
#define DH_   64
#define D_    8
#define FF_   3072
#define QKV3_ 2304
#define M_    (B_*L_)   // 16384 token rows

typedef __bf16   bf16;
typedef _Float16 f16;
typedef bf16  bf16x8 __attribute__((ext_vector_type(8)));
typedef f16   f16x8  __attribute__((ext_vector_type(8)));
typedef f16   half4  __attribute__((ext_vector_type(4)));
typedef float f32x4  __attribute__((ext_vector_type(4)));

// ---------------- sentinel (ws too small diagnostic) ----------------
__global__ void sentinel_kernel(float* out, int n){
    int i = blockIdx.x*64 + threadIdx.x;
    if (i < n) out[i] = 1.0e6f;
}

// ---------------- embed gather ----------------
__global__ __launch_bounds__(256) void gather_kernel(
    const int* __restrict__ tok, const float* __restrict__ emb, float* __restrict__ e)
{
    const int idx = blockIdx.x*256 + threadIdx.x;        // < M_*E_
    const int row = idx / E_;
    const int d   = idx - row*E_;
    e[idx] = emb[(size_t)tok[row]*E_ + d];
}

// ---------------- weight transpose + hi/lo split: W (K x N) -> planes (N x K) ----------------
template<typename T>
__global__ void wsplit_kernel(const float* __restrict__ W, T* __restrict__ Hh,
                              T* __restrict__ Ll, int K, int N)
{
    __shared__ float tile[32][33];
    const int tx = threadIdx.x, ty = threadIdx.y;        // 32 x 8
#pragma unroll
    for (int i2 = 0; i2 < 4; ++i2){
        const int k = blockIdx.y*32 + ty + i2*8;
        const int n = blockIdx.x*32 + tx;
        tile[ty + i2*8][tx] = W[(size_t)k*N + n];
    }
    __syncthreads();
    const int k2 = blockIdx.y*32 + tx;
#pragma unroll
    for (int i2 = 0; i2 < 4; ++i2){
        const int n2 = blockIdx.x*32 + ty + i2*8;
        const float v = tile[tx][ty + i2*8];
        const T hi = (T)v;
        const size_t idx = (size_t)n2*K + k2;
        Hh[idx] = hi;
        Ll[idx] = (T)(v - (float)hi);
    }
}

// ---------------- layernorm over E=768: optional f32 out + optional hi/lo bf16 planes ----------------
__global__ __launch_bounds__(256) void ln_kernel(
    const float* __restrict__ x, const float* __restrict__ g, const float* __restrict__ bb,
    float* __restrict__ yF, bf16* __restrict__ yH, bf16* __restrict__ yL)
{
    __shared__ float red[256];
    const int row = blockIdx.x, tid = threadIdx.x;
    const float* xr = x + (size_t)row*E_;
    float v0 = xr[tid], v1 = xr[tid+256], v2 = xr[tid+512];
    red[tid] = v0 + v1 + v2;
    __syncthreads();
    for (int o = 128; o; o >>= 1){ if (tid < o) red[tid] += red[tid+o]; __syncthreads(); }
    const float mean = red[0] * (1.f/768.f);
    __syncthreads();
    const float d0 = v0-mean, d1 = v1-mean, d2 = v2-mean;
    red[tid] = d0*d0 + d1*d1 + d2*d2;
    __syncthreads();
    for (int o = 128; o; o >>= 1){ if (tid < o) red[tid] += red[tid+o]; __syncthreads(); }
    const float rstd = rsqrtf(red[0]*(1.f/768.f) + 1e-5f);
    const float dv[3] = {d0, d1, d2};
#pragma unroll
    for (int q = 0; q < 3; ++q){
        const int d = tid + q*256;
        const float y = dv[q]*rstd*g[d] + bb[d];
        const size_t idx = (size_t)row*E_ + d;
        if (yF) yF[idx] = y;
        if (yH){
            const bf16 hi = (bf16)y;
            yH[idx] = hi;
            yL[idx] = (bf16)(y - (float)hi);
        }
    }
}

// ---------------- split-bf16 GEMM: C = (Ah+Al) @ (Bh+Bl)^T + bias (+epilogue) ----------------
// A planes: Mn x Kn row-major. B planes transposed: Nn x Kn row-major.
// MODE 0: Cf = v (qkv)   MODE 1: Cf = v + exH+exL (attn-out + e0 residual)
// MODE 2: Cq = (f16)relu(v) (MLP hidden)
template<int MODE>
__global__ __launch_bounds__(256, 2) void gemm3_kernel(
    const bf16* __restrict__ Ah, const bf16* __restrict__ Al,
    const bf16* __restrict__ Bh, const bf16* __restrict__ Bl,
    const float* __restrict__ bias,
    const bf16* __restrict__ exH, const bf16* __restrict__ exL,
    float* __restrict__ Cf, f16* __restrict__ Cq,
    int Mn, int Nn, int Kn)
{
    __shared__ bf16 sAh[128*32];
    __shared__ bf16 sAl[128*32];
    __shared__ bf16 sBh[128*32];
    __shared__ bf16 sBl[128*32];
    const int tid = threadIdx.x;
    const int w = tid >> 6, l = tid & 63;
    const int m0 = blockIdx.y * 128, n0 = blockIdx.x * 128;
    const int waveM = (w & 1) * 64, waveN = (w >> 1) * 64;
    const int fr = l & 15, fq = l >> 4;
    f32x4 acc[4][4] = {};

    const int e0i = tid * 8;            // staging chunk 0 (8 elems = 16B)
    const int r0  = e0i >> 5, k0o = e0i & 31;
    const int e1i = e0i + 2048;         // staging chunk 1
    const int r1  = e1i >> 5, k1o = e1i & 31;

    for (int kk = 0; kk < Kn; kk += 32){
        __syncthreads();
        {
            const size_t a0 = (size_t)(m0 + r0) * Kn + kk + k0o;
            const size_t a1 = (size_t)(m0 + r1) * Kn + kk + k1o;
            const size_t b0 = (size_t)(n0 + r0) * Kn + kk + k0o;
            const size_t b1 = (size_t)(n0 + r1) * Kn + kk + k1o;
            *(uint4*)&sAh[e0i] = *(const uint4*)&Ah[a0];
            *(uint4*)&sAh[e1i] = *(const uint4*)&Ah[a1];
            *(uint4*)&sAl[e0i] = *(const uint4*)&Al[a0];
            *(uint4*)&sAl[e1i] = *(const uint4*)&Al[a1];
            *(uint4*)&sBh[e0i] = *(const uint4*)&Bh[b0];
            *(uint4*)&sBh[e1i] = *(const uint4*)&Bh[b1];
            *(uint4*)&sBl[e0i] = *(const uint4*)&Bl[b0];
            *(uint4*)&sBl[e1i] = *(const uint4*)&Bl[b1];
        }
        __syncthreads();
        bf16x8 fah[4], fal[4], fbh[4], fbl[4];
#pragma unroll
        for (int i = 0; i < 4; ++i){
            fah[i] = *(const bf16x8*)&sAh[(waveM + i*16 + fr)*32 + fq*8];
            fal[i] = *(const bf16x8*)&sAl[(waveM + i*16 + fr)*32 + fq*8];
            fbh[i] = *(const bf16x8*)&sBh[(waveN + i*16 + fr)*32 + fq*8];
            fbl[i] = *(const bf16x8*)&sBl[(waveN + i*16 + fr)*32 + fq*8];
        }
#pragma unroll
        for (int i = 0; i < 4; ++i)
#pragma unroll
            for (int j = 0; j < 4; ++j){
                acc[i][j] = __builtin_amdgcn_mfma_f32_16x16x32_bf16(fah[i], fbh[j], acc[i][j], 0,0,0);
                acc[i][j] = __builtin_amdgcn_mfma_f32_16x16x32_bf16(fal[i], fbh[j], acc[i][j], 0,0,0);
                acc[i][j] = __builtin_amdgcn_mfma_f32_16x16x32_bf16(fah[i], fbl[j], acc[i][j], 0,0,0);
            }
    }
    // epilogue: C/D layout col=lane&15, row=(lane>>4)*4+reg [m89/m91-verified]
#pragma unroll
    for (int j = 0; j < 4; ++j){
        const int col = n0 + waveN + j*16 + fr;
        const float bc = bias[col];
#pragma unroll
        for (int i = 0; i < 4; ++i)
#pragma unroll
            for (int rg = 0; rg < 4; ++rg){
                const int row = m0 + waveM + i*16 + fq*4 + rg;
                const size_t idx = (size_t)row * Nn + col;
                float v = acc[i][j][rg] + bc;
                if (MODE == 0){
                    Cf[idx] = v;
                } else if (MODE == 1){
                    Cf[idx] = v + (float)exH[idx] + (float)exL[idx];
                } else {
                    Cq[idx] = (f16)fmaxf(v, 0.f);
                }
            }
    }
}

// ---------------- f16 GEMM (W2): C = A_f16 @ (Bh+Bl)^T + bias, pad-zero, + (exH+exL) ----------------
__global__ __launch_bounds__(256, 2) void gemm2_f16_kernel(
    const f16* __restrict__ A, const f16* __restrict__ Bh, const f16* __restrict__ Bl,
    const float* __restrict__ bias,
    const bf16* __restrict__ exH, const bf16* __restrict__ exL,
    const unsigned char* __restrict__ pad,
    float* __restrict__ Cf, int Mn, int Nn, int Kn)
{
    __shared__ f16 sA [128*32];
    __shared__ f16 sBh[128*32];
    __shared__ f16 sBl[128*32];
    const int tid = threadIdx.x;
    const int w = tid >> 6, l = tid & 63;
    const int m0 = blockIdx.y * 128, n0 = blockIdx.x * 128;
    const int waveM = (w & 1) * 64, waveN = (w >> 1) * 64;
    const int fr = l & 15, fq = l >> 4;
    f32x4 acc[4][4] = {};

    const int e0i = tid * 8;
    const int r0  = e0i >> 5, k0o = e0i & 31;
    const int e1i = e0i + 2048;
    const int r1  = e1i >> 5, k1o = e1i & 31;

    for (int kk = 0; kk < Kn; kk += 32){
        __syncthreads();
        {
            const size_t a0 = (size_t)(m0 + r0) * Kn + kk + k0o;
            const size_t a1 = (size_t)(m0 + r1) * Kn + kk + k1o;
            const size_t b0 = (size_t)(n0 + r0) * Kn + kk + k0o;
            const size_t b1 = (size_t)(n0 + r1) * Kn + kk + k1o;
            *(uint4*)&sA [e0i] = *(const uint4*)&A [a0];
            *(uint4*)&sA [e1i] = *(const uint4*)&A [a1];
            *(uint4*)&sBh[e0i] = *(const uint4*)&Bh[b0];
            *(uint4*)&sBh[e1i] = *(const uint4*)&Bh[b1];
            *(uint4*)&sBl[e0i] = *(const uint4*)&Bl[b0];
            *(uint4*)&sBl[e1i] = *(const uint4*)&Bl[b1];
        }
        __syncthreads();
        f16x8 fa[4], fbh[4], fbl[4];
#pragma unroll
        for (int i = 0; i < 4; ++i){
            fa[i]  = *(const f16x8*)&sA [(waveM + i*16 + fr)*32 + fq*8];
            fbh[i] = *(const f16x8*)&sBh[(waveN + i*16 + fr)*32 + fq*8];
            fbl[i] = *(const f16x8*)&sBl[(waveN + i*16 + fr)*32 + fq*8];
        }
#pragma unroll
        for (int i = 0; i < 4; ++i)
#pragma unroll
            for (int j = 0; j < 4; ++j){
                acc[i][j] = __builtin_amdgcn_mfma_f32_16x16x32_f16(fa[i], fbh[j], acc[i][j], 0,0,0);
                acc[i][j] = __builtin_amdgcn_mfma_f32_16x16x32_f16(fa[i], fbl[j], acc[i][j], 0,0,0);
            }
    }
#pragma unroll
    for (int i = 0; i < 4; ++i)
#pragma unroll
        for (int rg = 0; rg < 4; ++rg){
            const int row = m0 + waveM + i*16 + fq*4 + rg;
            const bool pz = pad[row] != 0;
#pragma unroll
            for (int j = 0; j < 4; ++j){
                const int col = n0 + waveN + j*16 + fr;
                const size_t idx = (size_t)row * Nn + col;
                float v = acc[i][j][rg] + bias[col];
                if (pz) v = 0.f;
                Cf[idx] = v + (float)exH[idx] + (float)exL[idx];
            }
        }
}

// ---------------- attention: block per (b,h); flash over 2 j-chunks; static LDS 63.5KB ----------------
__global__ __launch_bounds__(256, 2) void attn_kernel(
    const float* __restrict__ qkv, const float* __restrict__ rpos,
    const unsigned char* __restrict__ pad,
    const float* __restrict__ mu, const float* __restrict__ ga, const float* __restrict__ wv,
    bf16* __restrict__ Oh, bf16* __restrict__ Ol)
{
    __shared__ float KV[8704];            // union: Kt[64][130] f32  OR  V[128][68] f32
    __shared__ f16   Pw[4*16*128];        // per-wave P chunk (unnormalized)
    __shared__ f16   qs[64*64];           // 64 q rows (f16)
    __shared__ float rx[256], ry[256], rz[256], pf[256];

    const int h = blockIdx.x, b = blockIdx.y;
    const int tid = threadIdx.x, w = tid >> 6, l = tid & 63;
    const float muh = mu[h], gah = ga[h], wh = wv[h];
    const int rowbase = b * L_;
    const float* qk = qkv + (size_t)rowbase * QKV3_;
    const int qofs = h*DH_, kofs = E_ + h*DH_, vofs = 2*E_ + h*DH_;
    const int jg = l >> 4, dg = l & 15;

    rx[tid] = rpos[(size_t)(rowbase+tid)*3 + 0];
    ry[tid] = rpos[(size_t)(rowbase+tid)*3 + 1];
    rz[tid] = rpos[(size_t)(rowbase+tid)*3 + 2];
    pf[tid] = pad[rowbase+tid] ? 1.f : 0.f;

    for (int p = 0; p < 4; ++p){            // 64 q-rows per pass
        __syncthreads();
        for (int rep = 0; rep < 16; ++rep){ // stage q: 64x64 f16
            const int idx = rep*256 + tid;
            const int row = idx >> 6, d = idx & 63;
            qs[idx] = (f16)qk[(size_t)(p*64+row)*QKV3_ + qofs + d];
        }
        float m_[16], l_[16];
        f32x4 ao[16] = {};
#pragma unroll
        for (int r = 0; r < 16; ++r){ m_[r] = -3.0e38f; l_[r] = 0.f; }

        for (int c = 0; c < 2; ++c){        // j-chunks of 128
            __syncthreads();
            for (int rep = 0; rep < 32; ++rep){   // stage Kt chunk [64 d][130 pad]
                const int idx = rep*256 + tid;
                const int j = idx >> 6, d = idx & 63;
                KV[d*130 + j] = qk[(size_t)(c*128+j)*QKV3_ + kofs + d];
            }
            __syncthreads();
            // ---- scores: wave w rows 0..15, lane owns j-pair (2l, 2l+1) of chunk ----
            float sc0[16] = {}, sc1[16] = {};
            for (int dq = 0; dq < 16; ++dq){
                float2 kt[4];
#pragma unroll
                for (int dd = 0; dd < 4; ++dd)
                    kt[dd] = *(const float2*)&KV[(dq*4+dd)*130 + 2*l];
#pragma unroll
                for (int r = 0; r < 16; ++r){
                    const half4 qh = *(const half4*)&qs[(w*16+r)*64 + dq*4];
#pragma unroll
                    for (int dd = 0; dd < 4; ++dd){
                        const float qv = (float)qh[dd];
                        sc0[r] += qv * kt[dd].x;
                        sc1[r] += qv * kt[dd].y;
                    }
                }
            }
            // ---- bias + mask + online softmax update ----
            const int j0 = c*128 + 2*l, j1 = j0 + 1;
            const float jx0 = rx[j0], jy0 = ry[j0], jz0 = rz[j0], jp0 = pf[j0];
            const float jx1 = rx[j1], jy1 = ry[j1], jz1 = rz[j1], jp1 = pf[j1];
#pragma unroll
            for (int r = 0; r < 16; ++r){
                const int i = p*64 + w*16 + r;
                const float ix = rx[i], iy = ry[i], iz = rz[i], ip = pf[i];
                float dx = ix-jx0, dy = iy-jy0, dz = iz-jz0;
                float dist = sqrtf(dx*dx + dy*dy + dz*dz + 1e-12f);
                float t0 = dist - muh;
                float s0 = sc0[r]*0.125f + wh*__expf(-gah*t0*t0);
                if ((j0 == i) | (ip != 0.f) | (jp0 != 0.f)) s0 = -1e9f;
                dx = ix-jx1; dy = iy-jy1; dz = iz-jz1;
                dist = sqrtf(dx*dx + dy*dy + dz*dz + 1e-12f);
                float t1 = dist - muh;
                float s1 = sc1[r]*0.125f + wh*__expf(-gah*t1*t1);
                if ((j1 == i) | (ip != 0.f) | (jp1 != 0.f)) s1 = -1e9f;
                float mx = fmaxf(s0, s1);
#pragma unroll
                for (int off = 32; off >= 1; off >>= 1) mx = fmaxf(mx, __shfl_xor(mx, off));
                const float mnew = fmaxf(m_[r], mx);
                const float alpha = __expf(m_[r] - mnew);
                m_[r] = mnew;
                const float p0 = __expf(s0 - mnew), p1 = __expf(s1 - mnew);
                float rs = p0 + p1;
#pragma unroll
                for (int off = 32; off >= 1; off >>= 1) rs += __shfl_xor(rs, off);
                l_[r] = l_[r]*alpha + rs;
                ao[r][0] *= alpha; ao[r][1] *= alpha; ao[r][2] *= alpha; ao[r][3] *= alpha;
                union { f16 v[2]; unsigned u; } pk;
                pk.v[0] = (f16)p0; pk.v[1] = (f16)p1;
                *(unsigned*)&Pw[(w*16+r)*128 + 2*l] = pk.u;
            }
            __syncthreads();
            for (int rep = 0; rep < 32; ++rep){   // stage V chunk [128 j][68 pad] over Kt
                const int idx = rep*256 + tid;
                const int j = idx >> 6, d = idx & 63;
                KV[j*68 + d] = qk[(size_t)(c*128+j)*QKV3_ + vofs + d];
            }
            __syncthreads();
            // ---- P@V: lane (jg,dg): j-window jg*32..+31, dims dg*4..+3 ----
            for (int jq = 0; jq < 8; ++jq){
                f32x4 vr[4];
#pragma unroll
                for (int t = 0; t < 4; ++t)
                    vr[t] = *(const f32x4*)&KV[(jg*32 + jq*4 + t)*68 + dg*4];
#pragma unroll
                for (int r = 0; r < 16; ++r){
                    const half4 ph = *(const half4*)&Pw[(w*16+r)*128 + jg*32 + jq*4];
#pragma unroll
                    for (int t = 0; t < 4; ++t){
                        const float pv = (float)ph[t];
                        ao[r][0] += pv*vr[t][0]; ao[r][1] += pv*vr[t][1];
                        ao[r][2] += pv*vr[t][2]; ao[r][3] += pv*vr[t][3];
                    }
                }
            }
        } // chunks
        // reduce over jg partials; write o as split-bf16 planes
#pragma unroll
        for (int r = 0; r < 16; ++r)
#pragma unroll
            for (int t = 0; t < 4; ++t){
                float v = ao[r][t];
                v += __shfl_xor(v, 16);
                v += __shfl_xor(v, 32);
                ao[r][t] = v;
            }
        if (jg == 0){
#pragma unroll
            for (int r = 0; r < 16; ++r){
                const float inv = 1.f / l_[r];
                const size_t base = (size_t)(rowbase + p*64 + w*16 + r)*E_ + h*DH_ + dg*4;
                union { bf16 v[4]; uint2 u; } hv, lv;
#pragma unroll
                for (int t = 0; t < 4; ++t){
                    const float v = ao[r][t]*inv;
                    const bf16 hi = (bf16)v;
                    hv.v[t] = hi;
                    lv.v[t] = (bf16)(v - (float)hi);
                }
                *(uint2*)&Oh[base] = hv.u;
                *(uint2*)&Ol[base] = lv.u;
            }
        }
    } // passes
}

// ---------------- mean over L per (b, dim) ----------------
__global__ __launch_bounds__(256) void mean_kernel(const float* __restrict__ x, float* __restrict__ m)
{
    const int b = blockIdx.x, tid = threadIdx.x;
    const float* xb = x + (size_t)b*L_*E_;
#pragma unroll
    for (int q = 0; q < 3; ++q){
        const int d = tid + q*256;
        float s = 0.f;
        for (int l2 = 0; l2 < L_; ++l2) s += xb[(size_t)l2*E_ + d];
        m[b*E_ + d] = s * (1.f/(float)L_);
    }
}

// ---------------- final projection ----------------
__global__ __launch_bounds__(256) void out_kernel(
    const float* __restrict__ m, const float* __restrict__ Wout,
    const float* __restrict__ bout, float* __restrict__ out)
{
    __shared__ float red[256];
    const int b = blockIdx.x, tid = threadIdx.x;
    float s = 0.f;
#pragma unroll
    for (int q = 0; q < 3; ++q){ const int d = tid + q*256; s += m[b*E_ + d]*Wout[d]; }
    red[tid] = s;
    __syncthreads();
    for (int o = 128; o; o >>= 1){ if (tid < o) red[tid] += red[tid+o]; __syncthreads(); }
    if (tid == 0) out[b] = red[0] + bout[0];
}

// ---------------- host ----------------
extern "C" void kernel_launch(void* const* d_in, const int* in_sizes, int n_in,
                              void* d_out, int out_size, void* d_ws, size_t ws_size,
                              hipStream_t stream)
{
    const int*            tokens  = (const int*)d_in[0];
    const unsigned char*  padding = (const unsigned char*)d_in[1];
    const float*          rpos    = (const float*)d_in[2];
    const float*          embed   = (const float*)d_in[3];
    const float*          mu      = (const float*)d_in[4];
    const float*          ga      = (const float*)d_in[5];
    const float*          wv      = (const float*)d_in[6];
    const float*          Wqkv    = (const float*)d_in[7];
    const float*          bqkv    = (const float*)d_in[8];
    const float*          Wo      = (const float*)d_in[9];
    const float*          bo      = (const float*)d_in[10];
    const float*          ln1g    = (const float*)d_in[11];
    const float*          ln1b    = (const float*)d_in[12];
    const float*          W1      = (const float*)d_in[13];
    const float*          b1      = (const float*)d_in[14];
    const float*          W2      = (const float*)d_in[15];
    const float*          b2      = (const float*)d_in[16];
    const float*          ln2g    = (const float*)d_in[17];
    const float*          ln2b    = (const float*)d_in[18];
    const float*          lnfg    = (const float*)d_in[19];
    const float*          lnfb    = (const float*)d_in[20];
    const float*          Wout    = (const float*)d_in[21];
    const float*          bout    = (const float*)d_in[22];
    float* out = (float*)d_out;
    (void)in_sizes; (void)n_in;

    char* ws = (char*)d_ws;
    size_t off = 0;
    auto alloc = [&](size_t bytes)->char*{
        char* p = ws + off;
        off += (bytes + 255) & ~(size_t)255;
        return p;
    };
    float* e     = (float*)alloc((size_t)M_*E_*4);       // residual stream (o planes alias here)
    float* sbuf  = (float*)alloc((size_t)M_*QKV3_*4);    // qkv; then s (f32) + hidden (f16)
    bf16*  actH  = (bf16*) alloc((size_t)M_*E_*2);       // LN planes (hi)
    bf16*  actL  = (bf16*) alloc((size_t)M_*E_*2);       // LN planes (lo)
    bf16*  wqh   = (bf16*) alloc((size_t)E_*QKV3_*2);
    bf16*  wql   = (bf16*) alloc((size_t)E_*QKV3_*2);
    bf16*  woh   = (bf16*) alloc((size_t)E_*E_*2);
    bf16*  wol   = (bf16*) alloc((size_t)E_*E_*2);
    bf16*  w1h   = (bf16*) alloc((size_t)E_*FF_*2);
    bf16*  w1l   = (bf16*) alloc((size_t)E_*FF_*2);
    f16*   w2h   = (f16*)  alloc((size_t)FF_*E_*2);
    f16*   w2l   = (f16*)  alloc((size_t)FF_*E_*2);
    float* meanb = (float*)alloc((size_t)B_*E_*4);
    const size_t required = off;

    if (ws_size < required){
        // diagnostic: absmax ~1e6 => workspace too small (not a crash)
        sentinel_kernel<<<dim3((out_size+63)/64), dim3(64), 0, stream>>>(out, out_size);
        return;
    }

    // aliases (lifetimes disjoint, see per-layer timeline)
    bf16* oH   = (bf16*)e;                                   // attn out planes over dead residual
    bf16* oL   = oH + (size_t)M_*E_;
    f16*  hbuf = (f16*)((char*)sbuf + (size_t)M_*E_*4);      // MLP hidden inside dead qkv region

    gather_kernel<<<dim3(M_*E_/256), dim3(256), 0, stream>>>(tokens, embed, e);

    for (int i = 0; i < D_; ++i){
        wsplit_kernel<bf16><<<dim3(QKV3_/32, E_/32), dim3(32,8), 0, stream>>>(
            Wqkv + (size_t)i*E_*QKV3_, wqh, wql, E_, QKV3_);
        wsplit_kernel<bf16><<<dim3(E_/32, E_/32), dim3(32,8), 0, stream>>>(
            Wo + (size_t)i*E_*E_, woh, wol, E_, E_);
        wsplit_kernel<bf16><<<dim3(FF_/32, E_/32), dim3(32,8), 0, stream>>>(
            W1 + (size_t)i*E_*FF_, w1h, w1l, E_, FF_);
        wsplit_kernel<f16><<<dim3(E_/32, FF_/32), dim3(32,8), 0, stream>>>(
            W2 + (size_t)i*FF_*E_, w2h, w2l, FF_, E_);

        // e0 = LN1(e) -> split planes only
        ln_kernel<<<dim3(M_), dim3(256), 0, stream>>>(e, ln1g + i*E_, ln1b + i*E_, nullptr, actH, actL);
        // qkv = e0 @ Wqkv + bqkv  (f32, full sbuf)
        gemm3_kernel<0><<<dim3(QKV3_/128, M_/128), dim3(256), 0, stream>>>(
            actH, actL, wqh, wql, bqkv + i*QKV3_, nullptr, nullptr, sbuf, nullptr, M_, QKV3_, E_);
        // attention -> o planes (alias e; e is dead until MODE-3 rewrite)
        attn_kernel<<<dim3(H_, B_), dim3(256), 0, stream>>>(
            sbuf, rpos, padding, mu + i*H_, ga + i*H_, wv + i*H_, oH, oL);
        // s = o @ Wo + bo + e0(planes)  -> sbuf[0 : M*E] f32
        gemm3_kernel<1><<<dim3(E_/128, M_/128), dim3(256), 0, stream>>>(
            oH, oL, woh, wol, bo + i*E_, actH, actL, sbuf, nullptr, M_, E_, E_);
        // e2 = LN2(s) -> split planes
        ln_kernel<<<dim3(M_), dim3(256), 0, stream>>>(sbuf, ln2g + i*E_, ln2b + i*E_, nullptr, actH, actL);
        // h = relu(e2 @ W1 + b1) -> f16 plane (inside sbuf, past s)
        gemm3_kernel<2><<<dim3(FF_/128, M_/128), dim3(256), 0, stream>>>(
            actH, actL, w1h, w1l, b1 + i*FF_, nullptr, nullptr, nullptr, hbuf, M_, FF_, E_);
        // e = where(pad,0, h @ W2 + b2) + e2(planes)
        gemm2_f16_kernel<<<dim3(E_/128, M_/128), dim3(256), 0, stream>>>(
            hbuf, w2h, w2l, b2 + i*E_, actH, actL, padding, e, M_, E_, FF_);
    }

    ln_kernel<<<dim3(M_), dim3(256), 0, stream>>>(e, lnfg, lnfb, sbuf, nullptr, nullptr);
    mean_kernel<<<dim3(B_), dim3(256), 0, stream>>>(sbuf, meanb);
    out_kernel<<<dim3(B_), dim3(256), 0, stream>>>(meanb, Wout, bout, out);
}

// Round 3
// 6026.680 us; speedup vs baseline: 1.7056x; 1.7056x over previous
//
#include <hip/hip_runtime.h>
#include <cstdint>
#include <cstddef>

// ---------------- problem constants ----------------
#define B_    64
#define L_    256
#define E_    768
#define H_    12
#define DH_   64
#define D_    8
#define FF_   3072
#define QKV3_ 2304
#define M_    (B_*L_)   // 16384 token rows

typedef _Float16 f16;
typedef f16   f16x8  __attribute__((ext_vector_type(8)));
typedef float f32x4  __attribute__((ext_vector_type(4)));

// ---------------- sentinel (ws too small diagnostic) ----------------
__global__ void sentinel_kernel(float* out, int n){
    int i = blockIdx.x*64 + threadIdx.x;
    if (i < n) out[i] = 1.0e6f;
}

// ---------------- embed gather ----------------
__global__ __launch_bounds__(256) void gather_kernel(
    const int* __restrict__ tok, const float* __restrict__ emb, float* __restrict__ e)
{
    const int idx = blockIdx.x*256 + threadIdx.x;
    const int row = idx / E_;
    const int d   = idx - row*E_;
    e[idx] = emb[(size_t)tok[row]*E_ + d];
}

// ---------------- weight transpose + hi/lo f16 split: W (K x N) -> planes (N x K) ----------------
__global__ void wsplit_kernel(const float* __restrict__ W, f16* __restrict__ Hh,
                              f16* __restrict__ Ll, int K, int N)
{
    __shared__ float tile[32][33];
    const int tx = threadIdx.x, ty = threadIdx.y;        // 32 x 8
#pragma unroll
    for (int i2 = 0; i2 < 4; ++i2){
        const int k = blockIdx.y*32 + ty + i2*8;
        const int n = blockIdx.x*32 + tx;
        tile[ty + i2*8][tx] = W[(size_t)k*N + n];
    }
    __syncthreads();
    const int k2 = blockIdx.y*32 + tx;
#pragma unroll
    for (int i2 = 0; i2 < 4; ++i2){
        const int n2 = blockIdx.x*32 + ty + i2*8;
        const float v = tile[tx][ty + i2*8];
        const f16 hi = (f16)v;
        const size_t idx = (size_t)n2*K + k2;
        Hh[idx] = hi;
        Ll[idx] = (f16)(v - (float)hi);
    }
}

// ---------------- layernorm over E=768: optional f32 out + optional hi/lo f16 planes ----------------
__global__ __launch_bounds__(256) void ln_kernel(
    const float* __restrict__ x, const float* __restrict__ g, const float* __restrict__ bb,
    float* __restrict__ yF, f16* __restrict__ yH, f16* __restrict__ yL)
{
    __shared__ float red[256];
    const int row = blockIdx.x, tid = threadIdx.x;
    const float* xr = x + (size_t)row*E_;
    float v0 = xr[tid], v1 = xr[tid+256], v2 = xr[tid+512];
    red[tid] = v0 + v1 + v2;
    __syncthreads();
    for (int o = 128; o; o >>= 1){ if (tid < o) red[tid] += red[tid+o]; __syncthreads(); }
    const float mean = red[0] * (1.f/768.f);
    __syncthreads();
    const float d0 = v0-mean, d1 = v1-mean, d2 = v2-mean;
    red[tid] = d0*d0 + d1*d1 + d2*d2;
    __syncthreads();
    for (int o = 128; o; o >>= 1){ if (tid < o) red[tid] += red[tid+o]; __syncthreads(); }
    const float rstd = rsqrtf(red[0]*(1.f/768.f) + 1e-5f);
    const float dv[3] = {d0, d1, d2};
#pragma unroll
    for (int q = 0; q < 3; ++q){
        const int d = tid + q*256;
        const float y = dv[q]*rstd*g[d] + bb[d];
        const size_t idx = (size_t)row*E_ + d;
        if (yF) yF[idx] = y;
        if (yH){
            const f16 hi = (f16)y;
            yH[idx] = hi;
            yL[idx] = (f16)(y - (float)hi);
        }
    }
}

// ---------------- f16 GEMM: C = A @ (Bh+Bl)^T + bias (+epilogue), 2 MFMA/tile ----------------
// A: Mn x Kn row-major f16. B planes transposed: Nn x Kn row-major f16.
// MODE 0 (QKV): scatter f16 -> qh/kh [b][h][256][64], vt [b][h][64][256]
// MODE 1 (Wo):  Cf = v + exH+exL (f32)
// MODE 2 (W1):  Cq = (f16)relu(v)
// MODE 3 (W2):  Cf = (pad?0:v) + exH+exL (f32)
template<int MODE>
__global__ __launch_bounds__(256, 2) void gemm_kernel(
    const f16* __restrict__ A, const f16* __restrict__ Bh, const f16* __restrict__ Bl,
    const float* __restrict__ bias,
    const f16* __restrict__ exH, const f16* __restrict__ exL,
    const unsigned char* __restrict__ pad,
    float* __restrict__ Cf, f16* __restrict__ Cq,
    f16* __restrict__ qh, f16* __restrict__ kh, f16* __restrict__ vt,
    int Mn, int Nn, int Kn)
{
    __shared__ f16 sA [128*32];
    __shared__ f16 sBh[128*32];
    __shared__ f16 sBl[128*32];
    const int tid = threadIdx.x;
    const int w = tid >> 6, l = tid & 63;
    const int m0 = blockIdx.y * 128, n0 = blockIdx.x * 128;
    const int waveM = (w & 1) * 64, waveN = (w >> 1) * 64;
    const int fr = l & 15, fq = l >> 4;
    f32x4 acc[4][4] = {};

    const int e0i = tid * 8;            // staging chunk 0 (8 f16 = 16B)
    const int r0  = e0i >> 5, k0o = e0i & 31;
    const int e1i = e0i + 2048;         // staging chunk 1
    const int r1  = e1i >> 5, k1o = e1i & 31;

    for (int kk = 0; kk < Kn; kk += 32){
        __syncthreads();
        {
            const size_t a0 = (size_t)(m0 + r0) * Kn + kk + k0o;
            const size_t a1 = (size_t)(m0 + r1) * Kn + kk + k1o;
            const size_t b0 = (size_t)(n0 + r0) * Kn + kk + k0o;
            const size_t b1 = (size_t)(n0 + r1) * Kn + kk + k1o;
            *(uint4*)&sA [e0i] = *(const uint4*)&A [a0];
            *(uint4*)&sA [e1i] = *(const uint4*)&A [a1];
            *(uint4*)&sBh[e0i] = *(const uint4*)&Bh[b0];
            *(uint4*)&sBh[e1i] = *(const uint4*)&Bh[b1];
            *(uint4*)&sBl[e0i] = *(const uint4*)&Bl[b0];
            *(uint4*)&sBl[e1i] = *(const uint4*)&Bl[b1];
        }
        __syncthreads();
        f16x8 fa[4], fbh[4], fbl[4];
#pragma unroll
        for (int i = 0; i < 4; ++i){
            fa[i]  = *(const f16x8*)&sA [(waveM + i*16 + fr)*32 + fq*8];
            fbh[i] = *(const f16x8*)&sBh[(waveN + i*16 + fr)*32 + fq*8];
            fbl[i] = *(const f16x8*)&sBl[(waveN + i*16 + fr)*32 + fq*8];
        }
#pragma unroll
        for (int i = 0; i < 4; ++i)
#pragma unroll
            for (int j = 0; j < 4; ++j){
                acc[i][j] = __builtin_amdgcn_mfma_f32_16x16x32_f16(fa[i], fbh[j], acc[i][j], 0,0,0);
                acc[i][j] = __builtin_amdgcn_mfma_f32_16x16x32_f16(fa[i], fbl[j], acc[i][j], 0,0,0);
            }
    }
    // epilogue: C/D layout col=lane&15, row=(lane>>4)*4+reg [m89/m91-verified]
#pragma unroll
    for (int jt = 0; jt < 4; ++jt){
        const int col = n0 + waveN + jt*16 + fr;
        const float bc = bias[col];
        int which = 0, hh = 0, dd = 0;
        if (MODE == 0){
            which = col / 768;
            const int hc = col - which*768;
            hh = hc >> 6; dd = hc & 63;
        }
#pragma unroll
        for (int it = 0; it < 4; ++it)
#pragma unroll
            for (int rg = 0; rg < 4; ++rg){
                const int row = m0 + waveM + it*16 + fq*4 + rg;
                float v = acc[it][jt][rg] + bc;
                if (MODE == 0){
                    const int bb2 = row >> 8, jj2 = row & 255;
                    const size_t bh = (size_t)bb2 * H_ + hh;
                    if (which == 0)      qh[(bh*256 + jj2)*64 + dd] = (f16)v;
                    else if (which == 1) kh[(bh*256 + jj2)*64 + dd] = (f16)v;
                    else                 vt[(bh*64 + dd)*256 + jj2] = (f16)v;
                } else {
                    const size_t idx = (size_t)row * Nn + col;
                    if (MODE == 1){
                        Cf[idx] = v + (float)exH[idx] + (float)exL[idx];
                    } else if (MODE == 2){
                        Cq[idx] = (f16)fmaxf(v, 0.f);
                    } else {
                        if (pad[row]) v = 0.f;
                        Cf[idx] = v + (float)exH[idx] + (float)exL[idx];
                    }
                }
            }
    }
}

// ---------------- MFMA flash attention: block per (b,h,p); p = 64-q-row quarter ----------------
// q/k: [b][h][256][64] f16; vt: [b][h][64][256] f16; o: [M][E] f16 (A-plane for Wo GEMM)
__global__ __launch_bounds__(256, 4) void attn_kernel(
    const f16* __restrict__ qh, const f16* __restrict__ kh, const f16* __restrict__ vt,
    const float* __restrict__ rpos, const unsigned char* __restrict__ pad,
    const float* __restrict__ mu, const float* __restrict__ ga, const float* __restrict__ wv,
    f16* __restrict__ o)
{
    __shared__ f16 sK[64*72];        // K chunk [j][d], pad 72
    __shared__ f16 sV[64*72];        // Vt chunk [d][j], pad 72
    __shared__ f16 sP[4][16*72];     // per-wave P rows (A-layout), pad 72
    __shared__ float rx[256], ry[256], rz[256], pf[256];

    const int h = blockIdx.x, b = blockIdx.y, p = blockIdx.z;
    const int tid = threadIdx.x, w = tid >> 6, l = tid & 63;
    const int fr = l & 15, fq = l >> 4;
    const float muh = mu[h], gah = ga[h], wh = wv[h];
    const size_t bh = (size_t)b * H_ + h;
    const int rowbase = b * L_;

    rx[tid] = rpos[(size_t)(rowbase+tid)*3 + 0];
    ry[tid] = rpos[(size_t)(rowbase+tid)*3 + 1];
    rz[tid] = rpos[(size_t)(rowbase+tid)*3 + 2];
    pf[tid] = pad[rowbase+tid] ? 1.f : 0.f;

    // Q fragments for this wave's 16 rows (A layout: m=fr, k=fq*8+j within 32-window)
    f16x8 fQ[2];
    {
        const int r = p*64 + w*16 + fr;
        const f16* qp = qh + (bh*256 + r)*64 + fq*8;
        fQ[0] = *(const f16x8*)(qp);
        fQ[1] = *(const f16x8*)(qp + 32);
    }

    float m_[4], l_[4];
    f32x4 oacc[4] = {};
#pragma unroll
    for (int rg = 0; rg < 4; ++rg){ m_[rg] = -3.0e38f; l_[rg] = 0.f; }
    __syncthreads();

    for (int c = 0; c < 4; ++c){     // j-chunks of 64
        __syncthreads();
        {   // stage K chunk + Vt chunk (each 64x64 f16)
            const int e0 = tid*8, e1 = e0 + 2048;
            const int kr0 = e0 >> 6, kd0 = e0 & 63;
            const int kr1 = e1 >> 6, kd1 = e1 & 63;
            *(uint4*)&sK[kr0*72 + kd0] = *(const uint4*)&kh[(bh*256 + c*64 + kr0)*64 + kd0];
            *(uint4*)&sK[kr1*72 + kd1] = *(const uint4*)&kh[(bh*256 + c*64 + kr1)*64 + kd1];
            *(uint4*)&sV[kr0*72 + kd0] = *(const uint4*)&vt[(bh*64 + kr0)*256 + c*64 + kd0];
            *(uint4*)&sV[kr1*72 + kd1] = *(const uint4*)&vt[(bh*64 + kr1)*256 + c*64 + kd1];
        }
        __syncthreads();
        // ---- S = Q K^T (16 rows x 64 cols) ----
        f32x4 sacc[4] = {};
#pragma unroll
        for (int nt = 0; nt < 4; ++nt)
#pragma unroll
            for (int kf = 0; kf < 2; ++kf){
                const f16x8 fb = *(const f16x8*)&sK[(nt*16 + fr)*72 + kf*32 + fq*8];
                sacc[nt] = __builtin_amdgcn_mfma_f32_16x16x32_f16(fQ[kf], fb, sacc[nt], 0,0,0);
            }
        // ---- bias + mask (C layout: col=fr, row=fq*4+rg) ----
        float sv[4][4];
        float rmax[4] = {-3.0e38f, -3.0e38f, -3.0e38f, -3.0e38f};
        const int ibase = p*64 + w*16 + fq*4;
#pragma unroll
        for (int nt = 0; nt < 4; ++nt){
            const int j = c*64 + nt*16 + fr;
            const float jx = rx[j], jy = ry[j], jz = rz[j], jp = pf[j];
#pragma unroll
            for (int rg = 0; rg < 4; ++rg){
                const int i = ibase + rg;
                const float dx = rx[i]-jx, dy = ry[i]-jy, dz = rz[i]-jz;
                const float dist = sqrtf(dx*dx + dy*dy + dz*dz + 1e-12f);
                const float t = dist - muh;
                float s = sacc[nt][rg]*0.125f + wh*__expf(-gah*t*t);
                if ((j == i) | (pf[i] != 0.f) | (jp != 0.f)) s = -1e9f;
                sv[nt][rg] = s;
                rmax[rg] = fmaxf(rmax[rg], s);
            }
        }
        // ---- online softmax update; P -> wave-private LDS (A layout) ----
#pragma unroll
        for (int rg = 0; rg < 4; ++rg){
#pragma unroll
            for (int off = 8; off >= 1; off >>= 1)
                rmax[rg] = fmaxf(rmax[rg], __shfl_xor(rmax[rg], off));
            const float mnew = fmaxf(m_[rg], rmax[rg]);
            const float alpha = __expf(m_[rg] - mnew);
            m_[rg] = mnew;
            l_[rg] *= alpha;
#pragma unroll
            for (int dt = 0; dt < 4; ++dt) oacc[dt][rg] *= alpha;
            float rs = 0.f;
#pragma unroll
            for (int nt = 0; nt < 4; ++nt){
                const float pv = __expf(sv[nt][rg] - mnew);
                sP[w][(fq*4 + rg)*72 + nt*16 + fr] = (f16)pv;
                rs += pv;
            }
#pragma unroll
            for (int off = 8; off >= 1; off >>= 1) rs += __shfl_xor(rs, off);
            l_[rg] += rs;
        }
        // ---- O += P @ V ----
#pragma unroll
        for (int kf = 0; kf < 2; ++kf){
            const f16x8 pa = *(const f16x8*)&sP[w][fr*72 + kf*32 + fq*8];
#pragma unroll
            for (int dt = 0; dt < 4; ++dt){
                const f16x8 vb = *(const f16x8*)&sV[(dt*16 + fr)*72 + kf*32 + fq*8];
                oacc[dt] = __builtin_amdgcn_mfma_f32_16x16x32_f16(pa, vb, oacc[dt], 0,0,0);
            }
        }
    }
    // ---- normalize + write o (f16 row-major [M][E]) ----
    const int rglob = rowbase + p*64 + w*16 + fq*4;
#pragma unroll
    for (int rg = 0; rg < 4; ++rg){
        const float inv = 1.f / l_[rg];
#pragma unroll
        for (int dt = 0; dt < 4; ++dt)
            o[(size_t)(rglob + rg)*E_ + h*64 + dt*16 + fr] = (f16)(oacc[dt][rg]*inv);
    }
}

// ---------------- mean over L per (b, dim) ----------------
__global__ __launch_bounds__(256) void mean_kernel(const float* __restrict__ x, float* __restrict__ m)
{
    const int b = blockIdx.x, tid = threadIdx.x;
    const float* xb = x + (size_t)b*L_*E_;
#pragma unroll
    for (int q = 0; q < 3; ++q){
        const int d = tid + q*256;
        float s = 0.f;
        for (int l2 = 0; l2 < L_; ++l2) s += xb[(size_t)l2*E_ + d];
        m[b*E_ + d] = s * (1.f/(float)L_);
    }
}

// ---------------- final projection ----------------
__global__ __launch_bounds__(256) void out_kernel(
    const float* __restrict__ m, const float* __restrict__ Wout,
    const float* __restrict__ bout, float* __restrict__ out)
{
    __shared__ float red[256];
    const int b = blockIdx.x, tid = threadIdx.x;
    float s = 0.f;
#pragma unroll
    for (int q = 0; q < 3; ++q){ const int d = tid + q*256; s += m[b*E_ + d]*Wout[d]; }
    red[tid] = s;
    __syncthreads();
    for (int o = 128; o; o >>= 1){ if (tid < o) red[tid] += red[tid+o]; __syncthreads(); }
    if (tid == 0) out[b] = red[0] + bout[0];
}

// ---------------- host ----------------
extern "C" void kernel_launch(void* const* d_in, const int* in_sizes, int n_in,
                              void* d_out, int out_size, void* d_ws, size_t ws_size,
                              hipStream_t stream)
{
    const int*            tokens  = (const int*)d_in[0];
    const unsigned char*  padding = (const unsigned char*)d_in[1];
    const float*          rpos    = (const float*)d_in[2];
    const float*          embed   = (const float*)d_in[3];
    const float*          mu      = (const float*)d_in[4];
    const float*          ga      = (const float*)d_in[5];
    const float*          wv      = (const float*)d_in[6];
    const float*          Wqkv    = (const float*)d_in[7];
    const float*          bqkv    = (const float*)d_in[8];
    const float*          Wo      = (const float*)d_in[9];
    const float*          bo      = (const float*)d_in[10];
    const float*          ln1g    = (const float*)d_in[11];
    const float*          ln1b    = (const float*)d_in[12];
    const float*          W1      = (const float*)d_in[13];
    const float*          b1      = (const float*)d_in[14];
    const float*          W2      = (const float*)d_in[15];
    const float*          b2      = (const float*)d_in[16];
    const float*          ln2g    = (const float*)d_in[17];
    const float*          ln2b    = (const float*)d_in[18];
    const float*          lnfg    = (const float*)d_in[19];
    const float*          lnfb    = (const float*)d_in[20];
    const float*          Wout    = (const float*)d_in[21];
    const float*          bout    = (const float*)d_in[22];
    float* out = (float*)d_out;
    (void)in_sizes; (void)n_in;

    char* ws = (char*)d_ws;
    size_t off = 0;
    auto alloc = [&](size_t bytes)->char*{
        char* p = ws + off;
        off += (bytes + 255) & ~(size_t)255;
        return p;
    };
    const size_t PLANE = (size_t)M_*E_;                 // 12.58M elems
    float* e     = (float*)alloc(PLANE*4);              // residual; also s (Wo out) mid-layer
    char*  big   = alloc(PLANE*2*4);                    // qh|kh|vt|o ; later hbuf; later lnf f32
    f16*   actH  = (f16*)alloc(PLANE*2);                // LN planes (hi; GEMM A operand)
    f16*   actL  = (f16*)alloc(PLANE*2);                // LN planes (lo; residual reconstruction)
    f16*   wqh   = (f16*)alloc((size_t)E_*QKV3_*2);
    f16*   wql   = (f16*)alloc((size_t)E_*QKV3_*2);
    f16*   woh   = (f16*)alloc((size_t)E_*E_*2);
    f16*   wol   = (f16*)alloc((size_t)E_*E_*2);
    f16*   w1h   = (f16*)alloc((size_t)E_*FF_*2);
    f16*   w1l   = (f16*)alloc((size_t)E_*FF_*2);
    f16*   w2h   = (f16*)alloc((size_t)FF_*E_*2);
    f16*   w2l   = (f16*)alloc((size_t)FF_*E_*2);
    float* meanb = (float*)alloc((size_t)B_*E_*4);
    const size_t required = off;

    if (ws_size < required){
        sentinel_kernel<<<dim3((out_size+63)/64), dim3(64), 0, stream>>>(out, out_size);
        return;
    }

    // aliases inside `big` (lifetimes disjoint):
    f16*   qh   = (f16*)big;                 // QKV gemm -> attn
    f16*   kh   = qh + PLANE;
    f16*   vt   = kh + PLANE;
    f16*   ob   = vt + PLANE;                // attn -> Wo gemm
    f16*   hbuf = (f16*)big;                 // W1 -> W2 (after qkv/o dead)
    float* lnfo = (float*)big;               // final LN out (first half)
    float* sbuf = e;                         // Wo-out f32 aliases residual (e dead LN1..MODE3)

    gather_kernel<<<dim3(M_*E_/256), dim3(256), 0, stream>>>(tokens, embed, e);

    for (int i = 0; i < D_; ++i){
        wsplit_kernel<<<dim3(QKV3_/32, E_/32), dim3(32,8), 0, stream>>>(
            Wqkv + (size_t)i*E_*QKV3_, wqh, wql, E_, QKV3_);
        wsplit_kernel<<<dim3(E_/32, E_/32), dim3(32,8), 0, stream>>>(
            Wo + (size_t)i*E_*E_, woh, wol, E_, E_);
        wsplit_kernel<<<dim3(FF_/32, E_/32), dim3(32,8), 0, stream>>>(
            W1 + (size_t)i*E_*FF_, w1h, w1l, E_, FF_);
        wsplit_kernel<<<dim3(E_/32, FF_/32), dim3(32,8), 0, stream>>>(
            W2 + (size_t)i*FF_*E_, w2h, w2l, FF_, E_);

        // e0 = LN1(e) -> f16 planes
        ln_kernel<<<dim3(M_), dim3(256), 0, stream>>>(e, ln1g + i*E_, ln1b + i*E_, nullptr, actH, actL);
        // qkv = e0 @ Wqkv + bqkv -> scattered f16 q/k/vt planes
        gemm_kernel<0><<<dim3(QKV3_/128, M_/128), dim3(256), 0, stream>>>(
            actH, wqh, wql, bqkv + i*QKV3_, nullptr, nullptr, nullptr,
            nullptr, nullptr, qh, kh, vt, M_, QKV3_, E_);
        // o = attention(q,k,v)  (MFMA flash)
        attn_kernel<<<dim3(H_, B_, 4), dim3(256), 0, stream>>>(
            qh, kh, vt, rpos, padding, mu + i*H_, ga + i*H_, wv + i*H_, ob);
        // s = o @ Wo + bo + e0  -> f32 (aliases e)
        gemm_kernel<1><<<dim3(E_/128, M_/128), dim3(256), 0, stream>>>(
            ob, woh, wol, bo + i*E_, actH, actL, nullptr,
            sbuf, nullptr, nullptr, nullptr, nullptr, M_, E_, E_);
        // e2 = LN2(s) -> f16 planes
        ln_kernel<<<dim3(M_), dim3(256), 0, stream>>>(sbuf, ln2g + i*E_, ln2b + i*E_, nullptr, actH, actL);
        // h = relu(e2 @ W1 + b1) -> f16 (aliases qkv region; qkv/o dead)
        gemm_kernel<2><<<dim3(FF_/128, M_/128), dim3(256), 0, stream>>>(
            actH, w1h, w1l, b1 + i*FF_, nullptr, nullptr, nullptr,
            nullptr, hbuf, nullptr, nullptr, nullptr, M_, FF_, E_);
        // e = where(pad,0, h @ W2 + b2) + e2 -> f32 (same buffer as s; s dead)
        gemm_kernel<3><<<dim3(E_/128, M_/128), dim3(256), 0, stream>>>(
            hbuf, w2h, w2l, b2 + i*E_, actH, actL, padding,
            e, nullptr, nullptr, nullptr, nullptr, M_, E_, FF_);
    }

    ln_kernel<<<dim3(M_), dim3(256), 0, stream>>>(e, lnfg, lnfb, lnfo, nullptr, nullptr);
    mean_kernel<<<dim3(B_), dim3(256), 0, stream>>>(lnfo, meanb);
    out_kernel<<<dim3(B_), dim3(256), 0, stream>>>(meanb, Wout, bout, out);
}

// Round 4
// 5053.644 us; speedup vs baseline: 2.0340x; 1.1925x over previous
//
#include <hip/hip_runtime.h>
#include <cstdint>
#include <cstddef>

// ---------------- problem constants ----------------
#define B_    64
#define L_    256
#define E_    768
#define H_    12
#define DH_   64
#define D_    8
#define FF_   3072
#define QKV3_ 2304
#define M_    (B_*L_)   // 16384 token rows

typedef _Float16 f16;
typedef f16   f16x8  __attribute__((ext_vector_type(8)));
typedef float f32x4  __attribute__((ext_vector_type(4)));

// ---------------- sentinel (ws too small diagnostic) ----------------
__global__ void sentinel_kernel(float* out, int n){
    int i = blockIdx.x*64 + threadIdx.x;
    if (i < n) out[i] = 1.0e6f;
}

// ---------------- embed gather ----------------
__global__ __launch_bounds__(256) void gather_kernel(
    const int* __restrict__ tok, const float* __restrict__ emb, float* __restrict__ e)
{
    const int idx = blockIdx.x*256 + threadIdx.x;
    const int row = idx / E_;
    const int d   = idx - row*E_;
    e[idx] = emb[(size_t)tok[row]*E_ + d];
}

// ---------------- weight transpose -> f16: W (K x N) -> (N x K) ----------------
__global__ void wsplit_kernel(const float* __restrict__ W, f16* __restrict__ Hh, int K, int N)
{
    __shared__ float tile[32][33];
    const int tx = threadIdx.x, ty = threadIdx.y;        // 32 x 8
#pragma unroll
    for (int i2 = 0; i2 < 4; ++i2){
        const int k = blockIdx.y*32 + ty + i2*8;
        const int n = blockIdx.x*32 + tx;
        tile[ty + i2*8][tx] = W[(size_t)k*N + n];
    }
    __syncthreads();
    const int k2 = blockIdx.y*32 + tx;
#pragma unroll
    for (int i2 = 0; i2 < 4; ++i2){
        const int n2 = blockIdx.x*32 + ty + i2*8;
        Hh[(size_t)n2*K + k2] = (f16)tile[tx][ty + i2*8];
    }
}

// ---------------- layernorm over E=768: optional f32 out + optional hi/lo f16 planes ----------------
__global__ __launch_bounds__(256) void ln_kernel(
    const float* __restrict__ x, const float* __restrict__ g, const float* __restrict__ bb,
    float* __restrict__ yF, f16* __restrict__ yH, f16* __restrict__ yL)
{
    __shared__ float red[256];
    const int row = blockIdx.x, tid = threadIdx.x;
    const float* xr = x + (size_t)row*E_;
    float v0 = xr[tid], v1 = xr[tid+256], v2 = xr[tid+512];
    red[tid] = v0 + v1 + v2;
    __syncthreads();
    for (int o = 128; o; o >>= 1){ if (tid < o) red[tid] += red[tid+o]; __syncthreads(); }
    const float mean = red[0] * (1.f/768.f);
    __syncthreads();
    const float d0 = v0-mean, d1 = v1-mean, d2 = v2-mean;
    red[tid] = d0*d0 + d1*d1 + d2*d2;
    __syncthreads();
    for (int o = 128; o; o >>= 1){ if (tid < o) red[tid] += red[tid+o]; __syncthreads(); }
    const float rstd = rsqrtf(red[0]*(1.f/768.f) + 1e-5f);
    const float dv[3] = {d0, d1, d2};
#pragma unroll
    for (int q = 0; q < 3; ++q){
        const int d = tid + q*256;
        const float y = dv[q]*rstd*g[d] + bb[d];
        const size_t idx = (size_t)row*E_ + d;
        if (yF) yF[idx] = y;
        if (yH){
            const f16 hi = (f16)y;
            yH[idx] = hi;
            yL[idx] = (f16)(y - (float)hi);
        }
    }
}

// ---------------- f16 GEMM (1-pass): C = A @ B^T + bias (+epilogue) ----------------
// A: Mn x Kn row-major f16. B transposed: Nn x Kn row-major f16.
// Block swizzle: all N-tiles of one M-tile land on one XCD (kills cross-XCD A re-fetch).
// MODE 0 (QKV): scatter f16 -> qh/kh [b][h][256][64], vt [b][h][64][256]
// MODE 1 (Wo):  Cf = v + exH+exL (f32)
// MODE 2 (W1):  Cq = (f16)relu(v)
// MODE 3 (W2):  Cf = (pad?0:v) + exH+exL (f32)
template<int MODE>
__global__ __launch_bounds__(256, 4) void gemm_kernel(
    const f16* __restrict__ A, const f16* __restrict__ Bh,
    const float* __restrict__ bias,
    const f16* __restrict__ exH, const f16* __restrict__ exL,
    const unsigned char* __restrict__ pad,
    float* __restrict__ Cf, f16* __restrict__ Cq,
    f16* __restrict__ qh, f16* __restrict__ kh, f16* __restrict__ vt,
    int Mn, int Nn, int Kn)
{
    __shared__ f16 sA[128*32];
    __shared__ f16 sB[128*32];
    const int tid = threadIdx.x;
    const int w = tid >> 6, l = tid & 63;
    // ---- XCD-aware swizzle: xcd = flat%8 fixed; within an XCD iterate n fastest ----
    const int nt = gridDim.x;
    const int flat = blockIdx.y * nt + blockIdx.x;
    const int xcd = flat & 7, grp = flat >> 3;
    const int bx = grp % nt;
    const int by = xcd + 8 * (grp / nt);      // gridDim.y multiple of 8
    const int m0 = by * 128, n0 = bx * 128;
    const int waveM = (w & 1) * 64, waveN = (w >> 1) * 64;
    const int fr = l & 15, fq = l >> 4;
    f32x4 acc[4][4] = {};

    const int e0i = tid * 8;            // staging chunk 0 (8 f16 = 16B)
    const int r0  = e0i >> 5, k0o = e0i & 31;
    const int e1i = e0i + 2048;         // staging chunk 1
    const int r1  = e1i >> 5, k1o = e1i & 31;

    for (int kk = 0; kk < Kn; kk += 32){
        __syncthreads();
        {
            const size_t a0 = (size_t)(m0 + r0) * Kn + kk + k0o;
            const size_t a1 = (size_t)(m0 + r1) * Kn + kk + k1o;
            const size_t b0 = (size_t)(n0 + r0) * Kn + kk + k0o;
            const size_t b1 = (size_t)(n0 + r1) * Kn + kk + k1o;
            *(uint4*)&sA[e0i] = *(const uint4*)&A [a0];
            *(uint4*)&sA[e1i] = *(const uint4*)&A [a1];
            *(uint4*)&sB[e0i] = *(const uint4*)&Bh[b0];
            *(uint4*)&sB[e1i] = *(const uint4*)&Bh[b1];
        }
        __syncthreads();
        f16x8 fa[4], fb[4];
#pragma unroll
        for (int i = 0; i < 4; ++i){
            fa[i] = *(const f16x8*)&sA[(waveM + i*16 + fr)*32 + fq*8];
            fb[i] = *(const f16x8*)&sB[(waveN + i*16 + fr)*32 + fq*8];
        }
#pragma unroll
        for (int i = 0; i < 4; ++i)
#pragma unroll
            for (int j = 0; j < 4; ++j)
                acc[i][j] = __builtin_amdgcn_mfma_f32_16x16x32_f16(fa[i], fb[j], acc[i][j], 0,0,0);
    }
    // epilogue: C/D layout col=lane&15, row=(lane>>4)*4+reg [m89/m91-verified]
#pragma unroll
    for (int jt = 0; jt < 4; ++jt){
        const int col = n0 + waveN + jt*16 + fr;
        const float bc = bias[col];
        int which = 0, hh = 0, dd = 0;
        if (MODE == 0){
            which = col / 768;
            const int hc = col - which*768;
            hh = hc >> 6; dd = hc & 63;
        }
#pragma unroll
        for (int it = 0; it < 4; ++it)
#pragma unroll
            for (int rg = 0; rg < 4; ++rg){
                const int row = m0 + waveM + it*16 + fq*4 + rg;
                float v = acc[it][jt][rg] + bc;
                if (MODE == 0){
                    const int bb2 = row >> 8, jj2 = row & 255;
                    const size_t bh = (size_t)bb2 * H_ + hh;
                    if (which == 0)      qh[(bh*256 + jj2)*64 + dd] = (f16)v;
                    else if (which == 1) kh[(bh*256 + jj2)*64 + dd] = (f16)v;
                    else                 vt[(bh*64 + dd)*256 + jj2] = (f16)v;
                } else {
                    const size_t idx = (size_t)row * Nn + col;
                    if (MODE == 1){
                        Cf[idx] = v + (float)exH[idx] + (float)exL[idx];
                    } else if (MODE == 2){
                        Cq[idx] = (f16)fmaxf(v, 0.f);
                    } else {
                        if (pad[row]) v = 0.f;
                        Cf[idx] = v + (float)exH[idx] + (float)exL[idx];
                    }
                }
            }
    }
}

// ---------------- MFMA flash attention: block per (b,h,p); p = 64-q-row quarter ----------------
__global__ __launch_bounds__(256, 4) void attn_kernel(
    const f16* __restrict__ qh, const f16* __restrict__ kh, const f16* __restrict__ vt,
    const float* __restrict__ rpos, const unsigned char* __restrict__ pad,
    const float* __restrict__ mu, const float* __restrict__ ga, const float* __restrict__ wv,
    f16* __restrict__ o)
{
    __shared__ f16 sK[64*72];        // K chunk [j][d], pad 72
    __shared__ f16 sV[64*72];        // Vt chunk [d][j], pad 72
    __shared__ f16 sP[4][16*72];     // per-wave P rows (A-layout), pad 72
    __shared__ float rx[256], ry[256], rz[256], pf[256];

    const int h = blockIdx.x, b = blockIdx.y, p = blockIdx.z;
    const int tid = threadIdx.x, w = tid >> 6, l = tid & 63;
    const int fr = l & 15, fq = l >> 4;
    const float muh = mu[h], gah = ga[h], wh = wv[h];
    const size_t bh = (size_t)b * H_ + h;
    const int rowbase = b * L_;

    rx[tid] = rpos[(size_t)(rowbase+tid)*3 + 0];
    ry[tid] = rpos[(size_t)(rowbase+tid)*3 + 1];
    rz[tid] = rpos[(size_t)(rowbase+tid)*3 + 2];
    pf[tid] = pad[rowbase+tid] ? 1.f : 0.f;

    f16x8 fQ[2];
    {
        const int r = p*64 + w*16 + fr;
        const f16* qp = qh + (bh*256 + r)*64 + fq*8;
        fQ[0] = *(const f16x8*)(qp);
        fQ[1] = *(const f16x8*)(qp + 32);
    }

    float m_[4], l_[4];
    f32x4 oacc[4] = {};
#pragma unroll
    for (int rg = 0; rg < 4; ++rg){ m_[rg] = -3.0e38f; l_[rg] = 0.f; }
    __syncthreads();

    for (int c = 0; c < 4; ++c){     // j-chunks of 64
        __syncthreads();
        {   // stage K chunk + Vt chunk (each 64x64 f16)
            const int e0 = tid*8, e1 = e0 + 2048;
            const int kr0 = e0 >> 6, kd0 = e0 & 63;
            const int kr1 = e1 >> 6, kd1 = e1 & 63;
            *(uint4*)&sK[kr0*72 + kd0] = *(const uint4*)&kh[(bh*256 + c*64 + kr0)*64 + kd0];
            *(uint4*)&sK[kr1*72 + kd1] = *(const uint4*)&kh[(bh*256 + c*64 + kr1)*64 + kd1];
            *(uint4*)&sV[kr0*72 + kd0] = *(const uint4*)&vt[(bh*64 + kr0)*256 + c*64 + kd0];
            *(uint4*)&sV[kr1*72 + kd1] = *(const uint4*)&vt[(bh*64 + kr1)*256 + c*64 + kd1];
        }
        __syncthreads();
        // ---- S = Q K^T ----
        f32x4 sacc[4] = {};
#pragma unroll
        for (int nt = 0; nt < 4; ++nt)
#pragma unroll
            for (int kf = 0; kf < 2; ++kf){
                const f16x8 fb = *(const f16x8*)&sK[(nt*16 + fr)*72 + kf*32 + fq*8];
                sacc[nt] = __builtin_amdgcn_mfma_f32_16x16x32_f16(fQ[kf], fb, sacc[nt], 0,0,0);
            }
        // ---- bias + mask ----
        float sv[4][4];
        float rmax[4] = {-3.0e38f, -3.0e38f, -3.0e38f, -3.0e38f};
        const int ibase = p*64 + w*16 + fq*4;
#pragma unroll
        for (int nt = 0; nt < 4; ++nt){
            const int j = c*64 + nt*16 + fr;
            const float jx = rx[j], jy = ry[j], jz = rz[j], jp = pf[j];
#pragma unroll
            for (int rg = 0; rg < 4; ++rg){
                const int i = ibase + rg;
                const float dx = rx[i]-jx, dy = ry[i]-jy, dz = rz[i]-jz;
                const float dist = sqrtf(dx*dx + dy*dy + dz*dz + 1e-12f);
                const float t = dist - muh;
                float s = sacc[nt][rg]*0.125f + wh*__expf(-gah*t*t);
                if ((j == i) | (pf[i] != 0.f) | (jp != 0.f)) s = -1e9f;
                sv[nt][rg] = s;
                rmax[rg] = fmaxf(rmax[rg], s);
            }
        }
        // ---- online softmax; P -> wave-private LDS (A layout) ----
#pragma unroll
        for (int rg = 0; rg < 4; ++rg){
#pragma unroll
            for (int off = 8; off >= 1; off >>= 1)
                rmax[rg] = fmaxf(rmax[rg], __shfl_xor(rmax[rg], off));
            const float mnew = fmaxf(m_[rg], rmax[rg]);
            const float alpha = __expf(m_[rg] - mnew);
            m_[rg] = mnew;
            l_[rg] *= alpha;
#pragma unroll
            for (int dt = 0; dt < 4; ++dt) oacc[dt][rg] *= alpha;
            float rs = 0.f;
#pragma unroll
            for (int nt = 0; nt < 4; ++nt){
                const float pv = __expf(sv[nt][rg] - mnew);
                sP[w][(fq*4 + rg)*72 + nt*16 + fr] = (f16)pv;
                rs += pv;
            }
#pragma unroll
            for (int off = 8; off >= 1; off >>= 1) rs += __shfl_xor(rs, off);
            l_[rg] += rs;
        }
        // ---- O += P @ V ----
#pragma unroll
        for (int kf = 0; kf < 2; ++kf){
            const f16x8 pa = *(const f16x8*)&sP[w][fr*72 + kf*32 + fq*8];
#pragma unroll
            for (int dt = 0; dt < 4; ++dt){
                const f16x8 vb = *(const f16x8*)&sV[(dt*16 + fr)*72 + kf*32 + fq*8];
                oacc[dt] = __builtin_amdgcn_mfma_f32_16x16x32_f16(pa, vb, oacc[dt], 0,0,0);
            }
        }
    }
    const int rglob = rowbase + p*64 + w*16 + fq*4;
#pragma unroll
    for (int rg = 0; rg < 4; ++rg){
        const float inv = 1.f / l_[rg];
#pragma unroll
        for (int dt = 0; dt < 4; ++dt)
            o[(size_t)(rglob + rg)*E_ + h*64 + dt*16 + fr] = (f16)(oacc[dt][rg]*inv);
    }
}

// ---------------- mean over L per (b, dim) ----------------
__global__ __launch_bounds__(256) void mean_kernel(const float* __restrict__ x, float* __restrict__ m)
{
    const int b = blockIdx.x, tid = threadIdx.x;
    const float* xb = x + (size_t)b*L_*E_;
#pragma unroll
    for (int q = 0; q < 3; ++q){
        const int d = tid + q*256;
        float s = 0.f;
        for (int l2 = 0; l2 < L_; ++l2) s += xb[(size_t)l2*E_ + d];
        m[b*E_ + d] = s * (1.f/(float)L_);
    }
}

// ---------------- final projection ----------------
__global__ __launch_bounds__(256) void out_kernel(
    const float* __restrict__ m, const float* __restrict__ Wout,
    const float* __restrict__ bout, float* __restrict__ out)
{
    __shared__ float red[256];
    const int b = blockIdx.x, tid = threadIdx.x;
    float s = 0.f;
#pragma unroll
    for (int q = 0; q < 3; ++q){ const int d = tid + q*256; s += m[b*E_ + d]*Wout[d]; }
    red[tid] = s;
    __syncthreads();
    for (int o = 128; o; o >>= 1){ if (tid < o) red[tid] += red[tid+o]; __syncthreads(); }
    if (tid == 0) out[b] = red[0] + bout[0];
}

// ---------------- host ----------------
extern "C" void kernel_launch(void* const* d_in, const int* in_sizes, int n_in,
                              void* d_out, int out_size, void* d_ws, size_t ws_size,
                              hipStream_t stream)
{
    const int*            tokens  = (const int*)d_in[0];
    const unsigned char*  padding = (const unsigned char*)d_in[1];
    const float*          rpos    = (const float*)d_in[2];
    const float*          embed   = (const float*)d_in[3];
    const float*          mu      = (const float*)d_in[4];
    const float*          ga      = (const float*)d_in[5];
    const float*          wv      = (const float*)d_in[6];
    const float*          Wqkv    = (const float*)d_in[7];
    const float*          bqkv    = (const float*)d_in[8];
    const float*          Wo      = (const float*)d_in[9];
    const float*          bo      = (const float*)d_in[10];
    const float*          ln1g    = (const float*)d_in[11];
    const float*          ln1b    = (const float*)d_in[12];
    const float*          W1      = (const float*)d_in[13];
    const float*          b1      = (const float*)d_in[14];
    const float*          W2      = (const float*)d_in[15];
    const float*          b2      = (const float*)d_in[16];
    const float*          ln2g    = (const float*)d_in[17];
    const float*          ln2b    = (const float*)d_in[18];
    const float*          lnfg    = (const float*)d_in[19];
    const float*          lnfb    = (const float*)d_in[20];
    const float*          Wout    = (const float*)d_in[21];
    const float*          bout    = (const float*)d_in[22];
    float* out = (float*)d_out;
    (void)in_sizes; (void)n_in;

    char* ws = (char*)d_ws;
    size_t off = 0;
    auto alloc = [&](size_t bytes)->char*{
        char* p = ws + off;
        off += (bytes + 255) & ~(size_t)255;
        return p;
    };
    const size_t PLANE = (size_t)M_*E_;                 // 12.58M elems
    float* e     = (float*)alloc(PLANE*4);              // residual; also s (Wo out) mid-layer
    char*  big   = alloc(PLANE*2*4);                    // qh|kh|vt|o ; later hbuf; later lnf f32
    f16*   actH  = (f16*)alloc(PLANE*2);                // LN planes (hi; GEMM A operand)
    f16*   actL  = (f16*)alloc(PLANE*2);                // LN planes (lo; residual reconstruction)
    f16*   wqh   = (f16*)alloc((size_t)E_*QKV3_*2);
    f16*   woh   = (f16*)alloc((size_t)E_*E_*2);
    f16*   w1h   = (f16*)alloc((size_t)E_*FF_*2);
    f16*   w2h   = (f16*)alloc((size_t)FF_*E_*2);
    float* meanb = (float*)alloc((size_t)B_*E_*4);
    const size_t required = off;

    if (ws_size < required){
        sentinel_kernel<<<dim3((out_size+63)/64), dim3(64), 0, stream>>>(out, out_size);
        return;
    }

    // aliases inside `big` (lifetimes disjoint):
    f16*   qh   = (f16*)big;                 // QKV gemm -> attn
    f16*   kh   = qh + PLANE;
    f16*   vt   = kh + PLANE;
    f16*   ob   = vt + PLANE;                // attn -> Wo gemm
    f16*   hbuf = (f16*)big;                 // W1 -> W2 (after qkv/o dead)
    float* lnfo = (float*)big;               // final LN out (first half)
    float* sbuf = e;                         // Wo-out f32 aliases residual (e dead LN1..MODE3)

    gather_kernel<<<dim3(M_*E_/256), dim3(256), 0, stream>>>(tokens, embed, e);

    for (int i = 0; i < D_; ++i){
        wsplit_kernel<<<dim3(QKV3_/32, E_/32), dim3(32,8), 0, stream>>>(
            Wqkv + (size_t)i*E_*QKV3_, wqh, E_, QKV3_);
        wsplit_kernel<<<dim3(E_/32, E_/32), dim3(32,8), 0, stream>>>(
            Wo + (size_t)i*E_*E_, woh, E_, E_);
        wsplit_kernel<<<dim3(FF_/32, E_/32), dim3(32,8), 0, stream>>>(
            W1 + (size_t)i*E_*FF_, w1h, E_, FF_);
        wsplit_kernel<<<dim3(E_/32, FF_/32), dim3(32,8), 0, stream>>>(
            W2 + (size_t)i*FF_*E_, w2h, FF_, E_);

        // e0 = LN1(e) -> f16 hi/lo planes
        ln_kernel<<<dim3(M_), dim3(256), 0, stream>>>(e, ln1g + i*E_, ln1b + i*E_, nullptr, actH, actL);
        // qkv = e0 @ Wqkv + bqkv -> scattered f16 q/k/vt planes
        gemm_kernel<0><<<dim3(QKV3_/128, M_/128), dim3(256), 0, stream>>>(
            actH, wqh, bqkv + i*QKV3_, nullptr, nullptr, nullptr,
            nullptr, nullptr, qh, kh, vt, M_, QKV3_, E_);
        // o = attention(q,k,v)
        attn_kernel<<<dim3(H_, B_, 4), dim3(256), 0, stream>>>(
            qh, kh, vt, rpos, padding, mu + i*H_, ga + i*H_, wv + i*H_, ob);
        // s = o @ Wo + bo + e0  -> f32 (aliases e)
        gemm_kernel<1><<<dim3(E_/128, M_/128), dim3(256), 0, stream>>>(
            ob, woh, bo + i*E_, actH, actL, nullptr,
            sbuf, nullptr, nullptr, nullptr, nullptr, M_, E_, E_);
        // e2 = LN2(s) -> f16 hi/lo planes
        ln_kernel<<<dim3(M_), dim3(256), 0, stream>>>(sbuf, ln2g + i*E_, ln2b + i*E_, nullptr, actH, actL);
        // h = relu(e2 @ W1 + b1) -> f16 (aliases qkv region)
        gemm_kernel<2><<<dim3(FF_/128, M_/128), dim3(256), 0, stream>>>(
            actH, w1h, b1 + i*FF_, nullptr, nullptr, nullptr,
            nullptr, hbuf, nullptr, nullptr, nullptr, M_, FF_, E_);
        // e = where(pad,0, h @ W2 + b2) + e2 -> f32 (same buffer as s)
        gemm_kernel<3><<<dim3(E_/128, M_/128), dim3(256), 0, stream>>>(
            hbuf, w2h, b2 + i*E_, actH, actL, padding,
            e, nullptr, nullptr, nullptr, nullptr, M_, E_, FF_);
    }

    ln_kernel<<<dim3(M_), dim3(256), 0, stream>>>(e, lnfg, lnfb, lnfo, nullptr, nullptr);
    mean_kernel<<<dim3(B_), dim3(256), 0, stream>>>(lnfo, meanb);
    out_kernel<<<dim3(B_), dim3(256), 0, stream>>>(meanb, Wout, bout, out);
}

// Round 5
// 4880.214 us; speedup vs baseline: 2.1063x; 1.0355x over previous
//
#include <hip/hip_runtime.h>
#include <cstdint>
#include <cstddef>

// ---------------- problem constants ----------------
#define B_    64
#define L_    256
#define E_    768
#define H_    12
#define DH_   64
#define D_    8
#define FF_   3072
#define QKV3_ 2304
#define M_    (B_*L_)   // 16384 token rows

typedef _Float16 f16;
typedef f16   f16x8  __attribute__((ext_vector_type(8)));
typedef float f32x4  __attribute__((ext_vector_type(4)));

// async global->LDS DMA, 16B per lane; LDS dest must be wave-uniform base + lane*16
__device__ __forceinline__ void gl_lds16(const void* g, void* l){
    __builtin_amdgcn_global_load_lds(
        (const __attribute__((address_space(1))) void*)g,
        (__attribute__((address_space(3))) void*)l, 16, 0, 0);
}

// ---------------- sentinel (ws too small diagnostic) ----------------
__global__ void sentinel_kernel(float* out, int n){
    int i = blockIdx.x*64 + threadIdx.x;
    if (i < n) out[i] = 1.0e6f;
}

// ---------------- embed gather ----------------
__global__ __launch_bounds__(256) void gather_kernel(
    const int* __restrict__ tok, const float* __restrict__ emb, float* __restrict__ e)
{
    const int idx = blockIdx.x*256 + threadIdx.x;
    const int row = idx / E_;
    const int d   = idx - row*E_;
    e[idx] = emb[(size_t)tok[row]*E_ + d];
}

// ---------------- weight transpose -> f16: W (K x N) -> (N x K) ----------------
__global__ void wsplit_kernel(const float* __restrict__ W, f16* __restrict__ Hh, int K, int N)
{
    __shared__ float tile[32][33];
    const int tx = threadIdx.x, ty = threadIdx.y;        // 32 x 8
#pragma unroll
    for (int i2 = 0; i2 < 4; ++i2){
        const int k = blockIdx.y*32 + ty + i2*8;
        const int n = blockIdx.x*32 + tx;
        tile[ty + i2*8][tx] = W[(size_t)k*N + n];
    }
    __syncthreads();
    const int k2 = blockIdx.y*32 + tx;
#pragma unroll
    for (int i2 = 0; i2 < 4; ++i2){
        const int n2 = blockIdx.x*32 + ty + i2*8;
        Hh[(size_t)n2*K + k2] = (f16)tile[tx][ty + i2*8];
    }
}

// ---------------- layernorm over E=768: optional f32 out + optional hi/lo f16 planes ----------------
__global__ __launch_bounds__(256) void ln_kernel(
    const float* __restrict__ x, const float* __restrict__ g, const float* __restrict__ bb,
    float* __restrict__ yF, f16* __restrict__ yH, f16* __restrict__ yL)
{
    __shared__ float red[256];
    const int row = blockIdx.x, tid = threadIdx.x;
    const float* xr = x + (size_t)row*E_;
    float v0 = xr[tid], v1 = xr[tid+256], v2 = xr[tid+512];
    red[tid] = v0 + v1 + v2;
    __syncthreads();
    for (int o = 128; o; o >>= 1){ if (tid < o) red[tid] += red[tid+o]; __syncthreads(); }
    const float mean = red[0] * (1.f/768.f);
    __syncthreads();
    const float d0 = v0-mean, d1 = v1-mean, d2 = v2-mean;
    red[tid] = d0*d0 + d1*d1 + d2*d2;
    __syncthreads();
    for (int o = 128; o; o >>= 1){ if (tid < o) red[tid] += red[tid+o]; __syncthreads(); }
    const float rstd = rsqrtf(red[0]*(1.f/768.f) + 1e-5f);
    const float dv[3] = {d0, d1, d2};
#pragma unroll
    for (int q = 0; q < 3; ++q){
        const int d = tid + q*256;
        const float y = dv[q]*rstd*g[d] + bb[d];
        const size_t idx = (size_t)row*E_ + d;
        if (yF) yF[idx] = y;
        if (yH){
            const f16 hi = (f16)y;
            yH[idx] = hi;
            yL[idx] = (f16)(y - (float)hi);
        }
    }
}

// ---------------- f16 GEMM (1-pass): C = A @ B^T + bias (+epilogue) ----------------
// A: Mn x Kn row-major f16. B transposed: Nn x Kn row-major f16.
// Staging via global_load_lds width=16 (m97 lever: 1.69x over VGPR round-trip).
// Block swizzle: all N-tiles of one M-tile land on one XCD (kills cross-XCD A re-fetch).
// MODE 0 (QKV): scatter f16 -> qh/kh [b][h][256][64], vt [b][h][64][256]
// MODE 1 (Wo):  Cf = v + exH+exL (f32)
// MODE 2 (W1):  Cq = (f16)relu(v)
// MODE 3 (W2):  Cf = (pad?0:v) + exH+exL (f32)
template<int MODE>
__global__ __launch_bounds__(256, 4) void gemm_kernel(
    const f16* __restrict__ A, const f16* __restrict__ Bh,
    const float* __restrict__ bias,
    const f16* __restrict__ exH, const f16* __restrict__ exL,
    const unsigned char* __restrict__ pad,
    float* __restrict__ Cf, f16* __restrict__ Cq,
    f16* __restrict__ qh, f16* __restrict__ kh, f16* __restrict__ vt,
    int Mn, int Nn, int Kn)
{
    __shared__ f16 sA[128*32];
    __shared__ f16 sB[128*32];
    const int tid = threadIdx.x;
    const int w = tid >> 6, l = tid & 63;
    // ---- XCD-aware swizzle: xcd = flat%8 fixed; within an XCD iterate n fastest ----
    const int nt = gridDim.x;
    const int flat = blockIdx.y * nt + blockIdx.x;
    const int xcd = flat & 7, grp = flat >> 3;
    const int bx = grp % nt;
    const int by = xcd + 8 * (grp / nt);      // gridDim.y multiple of 8
    const int m0 = by * 128, n0 = bx * 128;
    const int waveM = (w & 1) * 64, waveN = (w >> 1) * 64;
    const int fr = l & 15, fq = l >> 4;
    f32x4 acc[4][4] = {};

    const int e0i = tid * 8;            // staging chunk 0 (8 f16 = 16B per lane)
    const int r0  = e0i >> 5, k0o = e0i & 31;
    const int e1i = e0i + 2048;         // staging chunk 1
    const int r1  = e1i >> 5, k1o = e1i & 31;

    for (int kk = 0; kk < Kn; kk += 32){
        __syncthreads();
        {
            const size_t a0 = (size_t)(m0 + r0) * Kn + kk + k0o;
            const size_t a1 = (size_t)(m0 + r1) * Kn + kk + k1o;
            const size_t b0 = (size_t)(n0 + r0) * Kn + kk + k0o;
            const size_t b1 = (size_t)(n0 + r1) * Kn + kk + k1o;
            gl_lds16(A  + a0, &sA[e0i]);
            gl_lds16(A  + a1, &sA[e1i]);
            gl_lds16(Bh + b0, &sB[e0i]);
            gl_lds16(Bh + b1, &sB[e1i]);
        }
        __syncthreads();
        f16x8 fa[4], fb[4];
#pragma unroll
        for (int i = 0; i < 4; ++i){
            fa[i] = *(const f16x8*)&sA[(waveM + i*16 + fr)*32 + fq*8];
            fb[i] = *(const f16x8*)&sB[(waveN + i*16 + fr)*32 + fq*8];
        }
#pragma unroll
        for (int i = 0; i < 4; ++i)
#pragma unroll
            for (int j = 0; j < 4; ++j)
                acc[i][j] = __builtin_amdgcn_mfma_f32_16x16x32_f16(fa[i], fb[j], acc[i][j], 0,0,0);
    }
    // epilogue: C/D layout col=lane&15, row=(lane>>4)*4+reg [m89/m91-verified]
#pragma unroll
    for (int jt = 0; jt < 4; ++jt){
        const int col = n0 + waveN + jt*16 + fr;
        const float bc = bias[col];
        int which = 0, hh = 0, dd = 0;
        if (MODE == 0){
            which = col / 768;
            const int hc = col - which*768;
            hh = hc >> 6; dd = hc & 63;
        }
#pragma unroll
        for (int it = 0; it < 4; ++it)
#pragma unroll
            for (int rg = 0; rg < 4; ++rg){
                const int row = m0 + waveM + it*16 + fq*4 + rg;
                float v = acc[it][jt][rg] + bc;
                if (MODE == 0){
                    const int bb2 = row >> 8, jj2 = row & 255;
                    const size_t bh = (size_t)bb2 * H_ + hh;
                    if (which == 0)      qh[(bh*256 + jj2)*64 + dd] = (f16)v;
                    else if (which == 1) kh[(bh*256 + jj2)*64 + dd] = (f16)v;
                    else                 vt[(bh*64 + dd)*256 + jj2] = (f16)v;
                } else {
                    const size_t idx = (size_t)row * Nn + col;
                    if (MODE == 1){
                        Cf[idx] = v + (float)exH[idx] + (float)exL[idx];
                    } else if (MODE == 2){
                        Cq[idx] = (f16)fmaxf(v, 0.f);
                    } else {
                        if (pad[row]) v = 0.f;
                        Cf[idx] = v + (float)exH[idx] + (float)exL[idx];
                    }
                }
            }
    }
}

// ---------------- MFMA flash attention: block per (b,h,p); p = 64-q-row quarter ----------------
__global__ __launch_bounds__(256, 4) void attn_kernel(
    const f16* __restrict__ qh, const f16* __restrict__ kh, const f16* __restrict__ vt,
    const float* __restrict__ rpos, const unsigned char* __restrict__ pad,
    const float* __restrict__ mu, const float* __restrict__ ga, const float* __restrict__ wv,
    f16* __restrict__ o)
{
    __shared__ f16 sK[64*72];        // K chunk [j][d], pad 72
    __shared__ f16 sV[64*72];        // Vt chunk [d][j], pad 72
    __shared__ f16 sP[4][16*72];     // per-wave P rows (A-layout), pad 72
    __shared__ float rx[256], ry[256], rz[256], pf[256];

    const int h = blockIdx.x, b = blockIdx.y, p = blockIdx.z;
    const int tid = threadIdx.x, w = tid >> 6, l = tid & 63;
    const int fr = l & 15, fq = l >> 4;
    const float muh = mu[h], gah = ga[h], wh = wv[h];
    const size_t bh = (size_t)b * H_ + h;
    const int rowbase = b * L_;

    rx[tid] = rpos[(size_t)(rowbase+tid)*3 + 0];
    ry[tid] = rpos[(size_t)(rowbase+tid)*3 + 1];
    rz[tid] = rpos[(size_t)(rowbase+tid)*3 + 2];
    pf[tid] = pad[rowbase+tid] ? 1.f : 0.f;

    f16x8 fQ[2];
    {
        const int r = p*64 + w*16 + fr;
        const f16* qp = qh + (bh*256 + r)*64 + fq*8;
        fQ[0] = *(const f16x8*)(qp);
        fQ[1] = *(const f16x8*)(qp + 32);
    }

    float m_[4], l_[4];
    f32x4 oacc[4] = {};
#pragma unroll
    for (int rg = 0; rg < 4; ++rg){ m_[rg] = -3.0e38f; l_[rg] = 0.f; }
    __syncthreads();

    for (int c = 0; c < 4; ++c){     // j-chunks of 64
        __syncthreads();
        {   // stage K chunk + Vt chunk (each 64x64 f16)
            const int e0 = tid*8, e1 = e0 + 2048;
            const int kr0 = e0 >> 6, kd0 = e0 & 63;
            const int kr1 = e1 >> 6, kd1 = e1 & 63;
            *(uint4*)&sK[kr0*72 + kd0] = *(const uint4*)&kh[(bh*256 + c*64 + kr0)*64 + kd0];
            *(uint4*)&sK[kr1*72 + kd1] = *(const uint4*)&kh[(bh*256 + c*64 + kr1)*64 + kd1];
            *(uint4*)&sV[kr0*72 + kd0] = *(const uint4*)&vt[(bh*64 + kr0)*256 + c*64 + kd0];
            *(uint4*)&sV[kr1*72 + kd1] = *(const uint4*)&vt[(bh*64 + kr1)*256 + c*64 + kd1];
        }
        __syncthreads();
        // ---- S = Q K^T ----
        f32x4 sacc[4] = {};
#pragma unroll
        for (int nt = 0; nt < 4; ++nt)
#pragma unroll
            for (int kf = 0; kf < 2; ++kf){
                const f16x8 fb = *(const f16x8*)&sK[(nt*16 + fr)*72 + kf*32 + fq*8];
                sacc[nt] = __builtin_amdgcn_mfma_f32_16x16x32_f16(fQ[kf], fb, sacc[nt], 0,0,0);
            }
        // ---- bias + mask ----
        float sv[4][4];
        float rmax[4] = {-3.0e38f, -3.0e38f, -3.0e38f, -3.0e38f};
        const int ibase = p*64 + w*16 + fq*4;
#pragma unroll
        for (int nt = 0; nt < 4; ++nt){
            const int j = c*64 + nt*16 + fr;
            const float jx = rx[j], jy = ry[j], jz = rz[j], jp = pf[j];
#pragma unroll
            for (int rg = 0; rg < 4; ++rg){
                const int i = ibase + rg;
                const float dx = rx[i]-jx, dy = ry[i]-jy, dz = rz[i]-jz;
                const float dist = sqrtf(dx*dx + dy*dy + dz*dz + 1e-12f);
                const float t = dist - muh;
                float s = sacc[nt][rg]*0.125f + wh*__expf(-gah*t*t);
                if ((j == i) | (pf[i] != 0.f) | (jp != 0.f)) s = -1e9f;
                sv[nt][rg] = s;
                rmax[rg] = fmaxf(rmax[rg], s);
            }
        }
        // ---- online softmax; P -> wave-private LDS (A layout) ----
#pragma unroll
        for (int rg = 0; rg < 4; ++rg){
#pragma unroll
            for (int off = 8; off >= 1; off >>= 1)
                rmax[rg] = fmaxf(rmax[rg], __shfl_xor(rmax[rg], off));
            const float mnew = fmaxf(m_[rg], rmax[rg]);
            const float alpha = __expf(m_[rg] - mnew);
            m_[rg] = mnew;
            l_[rg] *= alpha;
#pragma unroll
            for (int dt = 0; dt < 4; ++dt) oacc[dt][rg] *= alpha;
            float rs = 0.f;
#pragma unroll
            for (int nt = 0; nt < 4; ++nt){
                const float pv = __expf(sv[nt][rg] - mnew);
                sP[w][(fq*4 + rg)*72 + nt*16 + fr] = (f16)pv;
                rs += pv;
            }
#pragma unroll
            for (int off = 8; off >= 1; off >>= 1) rs += __shfl_xor(rs, off);
            l_[rg] += rs;
        }
        // ---- O += P @ V ----
#pragma unroll
        for (int kf = 0; kf < 2; ++kf){
            const f16x8 pa = *(const f16x8*)&sP[w][fr*72 + kf*32 + fq*8];
#pragma unroll
            for (int dt = 0; dt < 4; ++dt){
                const f16x8 vb = *(const f16x8*)&sV[(dt*16 + fr)*72 + kf*32 + fq*8];
                oacc[dt] = __builtin_amdgcn_mfma_f32_16x16x32_f16(pa, vb, oacc[dt], 0,0,0);
            }
        }
    }
    const int rglob = rowbase + p*64 + w*16 + fq*4;
#pragma unroll
    for (int rg = 0; rg < 4; ++rg){
        const float inv = 1.f / l_[rg];
#pragma unroll
        for (int dt = 0; dt < 4; ++dt)
            o[(size_t)(rglob + rg)*E_ + h*64 + dt*16 + fr] = (f16)(oacc[dt][rg]*inv);
    }
}

// ---------------- mean over L per (b, dim) ----------------
__global__ __launch_bounds__(256) void mean_kernel(const float* __restrict__ x, float* __restrict__ m)
{
    const int b = blockIdx.x, tid = threadIdx.x;
    const float* xb = x + (size_t)b*L_*E_;
#pragma unroll
    for (int q = 0; q < 3; ++q){
        const int d = tid + q*256;
        float s = 0.f;
        for (int l2 = 0; l2 < L_; ++l2) s += xb[(size_t)l2*E_ + d];
        m[b*E_ + d] = s * (1.f/(float)L_);
    }
}

// ---------------- final projection ----------------
__global__ __launch_bounds__(256) void out_kernel(
    const float* __restrict__ m, const float* __restrict__ Wout,
    const float* __restrict__ bout, float* __restrict__ out)
{
    __shared__ float red[256];
    const int b = blockIdx.x, tid = threadIdx.x;
    float s = 0.f;
#pragma unroll
    for (int q = 0; q < 3; ++q){ const int d = tid + q*256; s += m[b*E_ + d]*Wout[d]; }
    red[tid] = s;
    __syncthreads();
    for (int o = 128; o; o >>= 1){ if (tid < o) red[tid] += red[tid+o]; __syncthreads(); }
    if (tid == 0) out[b] = red[0] + bout[0];
}

// ---------------- host ----------------
extern "C" void kernel_launch(void* const* d_in, const int* in_sizes, int n_in,
                              void* d_out, int out_size, void* d_ws, size_t ws_size,
                              hipStream_t stream)
{
    const int*            tokens  = (const int*)d_in[0];
    const unsigned char*  padding = (const unsigned char*)d_in[1];
    const float*          rpos    = (const float*)d_in[2];
    const float*          embed   = (const float*)d_in[3];
    const float*          mu      = (const float*)d_in[4];
    const float*          ga      = (const float*)d_in[5];
    const float*          wv      = (const float*)d_in[6];
    const float*          Wqkv    = (const float*)d_in[7];
    const float*          bqkv    = (const float*)d_in[8];
    const float*          Wo      = (const float*)d_in[9];
    const float*          bo      = (const float*)d_in[10];
    const float*          ln1g    = (const float*)d_in[11];
    const float*          ln1b    = (const float*)d_in[12];
    const float*          W1      = (const float*)d_in[13];
    const float*          b1      = (const float*)d_in[14];
    const float*          W2      = (const float*)d_in[15];
    const float*          b2      = (const float*)d_in[16];
    const float*          ln2g    = (const float*)d_in[17];
    const float*          ln2b    = (const float*)d_in[18];
    const float*          lnfg    = (const float*)d_in[19];
    const float*          lnfb    = (const float*)d_in[20];
    const float*          Wout    = (const float*)d_in[21];
    const float*          bout    = (const float*)d_in[22];
    float* out = (float*)d_out;
    (void)in_sizes; (void)n_in;

    char* ws = (char*)d_ws;
    size_t off = 0;
    auto alloc = [&](size_t bytes)->char*{
        char* p = ws + off;
        off += (bytes + 255) & ~(size_t)255;
        return p;
    };
    const size_t PLANE = (size_t)M_*E_;                 // 12.58M elems
    float* e     = (float*)alloc(PLANE*4);              // residual; also s (Wo out) mid-layer
    char*  big   = alloc(PLANE*2*4);                    // qh|kh|vt|o ; later hbuf; later lnf f32
    f16*   actH  = (f16*)alloc(PLANE*2);                // LN planes (hi; GEMM A operand)
    f16*   actL  = (f16*)alloc(PLANE*2);                // LN planes (lo; residual reconstruction)
    f16*   wqh   = (f16*)alloc((size_t)E_*QKV3_*2);
    f16*   woh   = (f16*)alloc((size_t)E_*E_*2);
    f16*   w1h   = (f16*)alloc((size_t)E_*FF_*2);
    f16*   w2h   = (f16*)alloc((size_t)FF_*E_*2);
    float* meanb = (float*)alloc((size_t)B_*E_*4);
    const size_t required = off;

    if (ws_size < required){
        sentinel_kernel<<<dim3((out_size+63)/64), dim3(64), 0, stream>>>(out, out_size);
        return;
    }

    // aliases inside `big` (lifetimes disjoint):
    f16*   qh   = (f16*)big;                 // QKV gemm -> attn
    f16*   kh   = qh + PLANE;
    f16*   vt   = kh + PLANE;
    f16*   ob   = vt + PLANE;                // attn -> Wo gemm
    f16*   hbuf = (f16*)big;                 // W1 -> W2 (after qkv/o dead)
    float* lnfo = (float*)big;               // final LN out (first half)
    float* sbuf = e;                         // Wo-out f32 aliases residual (e dead LN1..MODE3)

    gather_kernel<<<dim3(M_*E_/256), dim3(256), 0, stream>>>(tokens, embed, e);

    for (int i = 0; i < D_; ++i){
        wsplit_kernel<<<dim3(QKV3_/32, E_/32), dim3(32,8), 0, stream>>>(
            Wqkv + (size_t)i*E_*QKV3_, wqh, E_, QKV3_);
        wsplit_kernel<<<dim3(E_/32, E_/32), dim3(32,8), 0, stream>>>(
            Wo + (size_t)i*E_*E_, woh, E_, E_);
        wsplit_kernel<<<dim3(FF_/32, E_/32), dim3(32,8), 0, stream>>>(
            W1 + (size_t)i*E_*FF_, w1h, E_, FF_);
        wsplit_kernel<<<dim3(E_/32, FF_/32), dim3(32,8), 0, stream>>>(
            W2 + (size_t)i*FF_*E_, w2h, FF_, E_);

        // e0 = LN1(e) -> f16 hi/lo planes
        ln_kernel<<<dim3(M_), dim3(256), 0, stream>>>(e, ln1g + i*E_, ln1b + i*E_, nullptr, actH, actL);
        // qkv = e0 @ Wqkv + bqkv -> scattered f16 q/k/vt planes
        gemm_kernel<0><<<dim3(QKV3_/128, M_/128), dim3(256), 0, stream>>>(
            actH, wqh, bqkv + i*QKV3_, nullptr, nullptr, nullptr,
            nullptr, nullptr, qh, kh, vt, M_, QKV3_, E_);
        // o = attention(q,k,v)
        attn_kernel<<<dim3(H_, B_, 4), dim3(256), 0, stream>>>(
            qh, kh, vt, rpos, padding, mu + i*H_, ga + i*H_, wv + i*H_, ob);
        // s = o @ Wo + bo + e0  -> f32 (aliases e)
        gemm_kernel<1><<<dim3(E_/128, M_/128), dim3(256), 0, stream>>>(
            ob, woh, bo + i*E_, actH, actL, nullptr,
            sbuf, nullptr, nullptr, nullptr, nullptr, M_, E_, E_);
        // e2 = LN2(s) -> f16 hi/lo planes
        ln_kernel<<<dim3(M_), dim3(256), 0, stream>>>(sbuf, ln2g + i*E_, ln2b + i*E_, nullptr, actH, actL);
        // h = relu(e2 @ W1 + b1) -> f16 (aliases qkv region)
        gemm_kernel<2><<<dim3(FF_/128, M_/128), dim3(256), 0, stream>>>(
            actH, w1h, b1 + i*FF_, nullptr, nullptr, nullptr,
            nullptr, hbuf, nullptr, nullptr, nullptr, M_, FF_, E_);
        // e = where(pad,0, h @ W2 + b2) + e2 -> f32 (same buffer as s)
        gemm_kernel<3><<<dim3(E_/128, M_/128), dim3(256), 0, stream>>>(
            hbuf, w2h, b2 + i*E_, actH, actL, padding,
            e, nullptr, nullptr, nullptr, nullptr, M_, E_, FF_);
    }

    ln_kernel<<<dim3(M_), dim3(256), 0, stream>>>(e, lnfg, lnfb, lnfo, nullptr, nullptr);
    mean_kernel<<<dim3(B_), dim3(256), 0, stream>>>(lnfo, meanb);
    out_kernel<<<dim3(B_), dim3(256), 0, stream>>>(meanb, Wout, bout, out);
}